// Round 1
// baseline (255.375 us; speedup 1.0000x reference)
//
#include <hip/hip_runtime.h>

// Robust global pool: per 4096-elem slice, y* = argmin_y sum phi(y - x),
// phi = pseudo-Huber (alpha=1). Newton from mean init; converged fixed point
// is iteration-count independent, so 10 iters ≈ reference's 50.
//
// One block per slice; 256 threads x 16 floats held in registers.
// HBM read exactly once; all Newton iterations from registers.

#define NITER 10

__global__ __launch_bounds__(256)
void robust_pool_kernel(const float* __restrict__ x, float* __restrict__ out) {
    const int b = blockIdx.x;
    const int t = threadIdx.x;
    const int lane = t & 63;
    const int wid = t >> 6;

    // Coalesced load: 256 threads * 4 float4 = 4096 floats per slice.
    const float4* xs = reinterpret_cast<const float4*>(x + (size_t)b * 4096);
    float v[16];
    float4* vv = reinterpret_cast<float4*>(v);
    vv[0] = xs[t];
    vv[1] = xs[t + 256];
    vv[2] = xs[t + 512];
    vv[3] = xs[t + 768];

    __shared__ float2 part[4];

    // ---- mean init ----
    float s = 0.0f;
#pragma unroll
    for (int k = 0; k < 16; ++k) s += v[k];
#pragma unroll
    for (int off = 32; off; off >>= 1) s += __shfl_xor(s, off, 64);
    if (lane == 0) part[wid] = make_float2(s, 0.0f);
    __syncthreads();
    float y = (part[0].x + part[1].x + part[2].x + part[3].x) * (1.0f / 4096.0f);
    __syncthreads();

    // ---- Newton iterations (all data in registers) ----
#pragma unroll 1
    for (int it = 0; it < NITER; ++it) {
        float g = 0.0f, h = 0.0f;
#pragma unroll
        for (int k = 0; k < 16; ++k) {
            float z = y - v[k];
            float tt = fmaf(z, z, 1.0f);
            float r = rsqrtf(tt);       // t^-0.5
            g = fmaf(z, r, g);          // z / sqrt(t)
            float rr = r * r;
            h = fmaf(rr, r, h);         // t^-1.5
        }
        // wave butterfly: every lane ends with the wave sum
#pragma unroll
        for (int off = 32; off; off >>= 1) {
            g += __shfl_xor(g, off, 64);
            h += __shfl_xor(h, off, 64);
        }
        if (lane == 0) part[wid] = make_float2(g, h);
        __syncthreads();
        float G = part[0].x + part[1].x + part[2].x + part[3].x;
        float H = part[0].y + part[1].y + part[2].y + part[3].y;
        __syncthreads();
        y -= G / fmaxf(H, 1e-12f);
    }

    if (t == 0) out[b] = y;
}

extern "C" void kernel_launch(void* const* d_in, const int* in_sizes, int n_in,
                              void* d_out, int out_size, void* d_ws, size_t ws_size,
                              hipStream_t stream) {
    const float* x = (const float*)d_in[0];
    float* out = (float*)d_out;
    const int n_slices = in_sizes[0] >> 12;   // 4096 elements per slice
    robust_pool_kernel<<<n_slices, 256, 0, stream>>>(x, out);
}

// Round 2
// 189.680 us; speedup vs baseline: 1.3463x; 1.3463x over previous
//
#include <hip/hip_runtime.h>

// Robust global pool: per 4096-elem slice, y* = argmin_y sum phi(y - x),
// phi = pseudo-Huber (alpha=1). Newton from mean init converges quadratically:
// e0~1.6e-2 -> e1~3e-4 -> e2~1e-7 (fp32 floor). 4 iters = 1e4x margin vs the
// 1.27e-3 threshold (R1 measured: 10 iters -> absmax 1.19e-7 = round-off).
//
// One block per slice; 256 threads x 16 floats held in registers (VGPR=28,
// no spill per R1). HBM read exactly once; all Newton iterations from regs.
// __builtin_amdgcn_rsqf/rcpf force bare v_rsq_f32/v_rcp_f32 (no OCML expansion).

#define NITER 4

__global__ __launch_bounds__(256)
void robust_pool_kernel(const float* __restrict__ x, float* __restrict__ out) {
    const int b = blockIdx.x;
    const int t = threadIdx.x;
    const int lane = t & 63;
    const int wid = t >> 6;

    // Coalesced load: 256 threads * 4 float4 = 4096 floats per slice.
    const float4* xs = reinterpret_cast<const float4*>(x + (size_t)b * 4096);
    float v[16];
    float4* vv = reinterpret_cast<float4*>(v);
    vv[0] = xs[t];
    vv[1] = xs[t + 256];
    vv[2] = xs[t + 512];
    vv[3] = xs[t + 768];

    // Double-buffered cross-wave partials: one __syncthreads per iteration.
    __shared__ float2 part[2][4];

    // ---- mean init ----
    float s = 0.0f;
#pragma unroll
    for (int k = 0; k < 16; ++k) s += v[k];
#pragma unroll
    for (int off = 32; off; off >>= 1) s += __shfl_xor(s, off, 64);
    if (lane == 0) part[0][wid] = make_float2(s, 0.0f);
    __syncthreads();
    float y = (part[0][0].x + part[0][1].x + part[0][2].x + part[0][3].x)
              * (1.0f / 4096.0f);

    // ---- Newton iterations (all data in registers) ----
    int buf = 1;
#pragma unroll 1
    for (int it = 0; it < NITER; ++it) {
        float g = 0.0f, h = 0.0f;
#pragma unroll
        for (int k = 0; k < 16; ++k) {
            float z = y - v[k];
            float tt = fmaf(z, z, 1.0f);
            float r = __builtin_amdgcn_rsqf(tt);   // t^-0.5, single v_rsq_f32
            g = fmaf(z, r, g);                     // z / sqrt(t)
            h = fmaf(r * r, r, h);                 // t^-1.5
        }
        // wave butterfly: every lane ends with the wave sum
#pragma unroll
        for (int off = 32; off; off >>= 1) {
            g += __shfl_xor(g, off, 64);
            h += __shfl_xor(h, off, 64);
        }
        if (lane == 0) part[buf][wid] = make_float2(g, h);
        __syncthreads();
        float G = part[buf][0].x + part[buf][1].x + part[buf][2].x + part[buf][3].x;
        float H = part[buf][0].y + part[buf][1].y + part[buf][2].y + part[buf][3].y;
        y -= G * __builtin_amdgcn_rcpf(fmaxf(H, 1e-12f));
        buf ^= 1;
    }

    if (t == 0) out[b] = y;
}

extern "C" void kernel_launch(void* const* d_in, const int* in_sizes, int n_in,
                              void* d_out, int out_size, void* d_ws, size_t ws_size,
                              hipStream_t stream) {
    const float* x = (const float*)d_in[0];
    float* out = (float*)d_out;
    const int n_slices = in_sizes[0] >> 12;   // 4096 elements per slice
    robust_pool_kernel<<<n_slices, 256, 0, stream>>>(x, out);
}

// Round 3
// 185.931 us; speedup vs baseline: 1.3735x; 1.0202x over previous
//
#include <hip/hip_runtime.h>

// Robust global pool: per 4096-elem slice, y* = argmin_y sum phi(y - x),
// phi = pseudo-Huber (alpha=1). Newton from mean init converges quadratically:
// e0 = |mean - y*| <~ 1e-2 for 4096 N(0,1) samples -> e1 ~ 1e-4 -> e2 ~ 1e-7
// (fp32 floor). R2 measured: 4 iters -> absmax 1.19e-7 = round-off, so 2 iters
// keeps ~1000x margin vs the 1.27e-3 threshold.
//
// R3 structure: ONE WAVE per slice (64 threads x 64 floats in registers).
//  - reduction = pure in-register __shfl_xor butterfly: no LDS, no
//    __syncthreads, no cross-wave lockstep (R2's 11 us/iter vs ~4 us
//    arithmetic floor was barrier + dependent-shuffle-chain overhead;
//    independent waves now hide each other's shuffle latency).
//  - HBM read exactly once; all Newton iterations from registers.
//  - __builtin_amdgcn_rsqf/rcpf: bare v_rsq_f32/v_rcp_f32, no OCML expansion.

#define NITER 2

__global__ __launch_bounds__(64)
void robust_pool_kernel(const float* __restrict__ x, float* __restrict__ out) {
    const int b = blockIdx.x;
    const int t = threadIdx.x;          // 0..63, one wave

    // Coalesced load: 64 threads * 16 float4 = 4096 floats per slice.
    const float4* xs = reinterpret_cast<const float4*>(x + (size_t)b * 4096);
    float v[64];
    float4* vv = reinterpret_cast<float4*>(v);
#pragma unroll
    for (int k = 0; k < 16; ++k) vv[k] = xs[t + 64 * k];

    // ---- mean init (in-register butterfly) ----
    float s = 0.0f;
#pragma unroll
    for (int k = 0; k < 64; ++k) s += v[k];
#pragma unroll
    for (int off = 32; off; off >>= 1) s += __shfl_xor(s, off, 64);
    float y = s * (1.0f / 4096.0f);

    // ---- Newton iterations (all data in registers, wave-local) ----
#pragma unroll 1
    for (int it = 0; it < NITER; ++it) {
        float g = 0.0f, h = 0.0f;
#pragma unroll
        for (int k = 0; k < 64; ++k) {
            float z = y - v[k];
            float tt = fmaf(z, z, 1.0f);
            float r = __builtin_amdgcn_rsqf(tt);   // t^-0.5, single v_rsq_f32
            g = fmaf(z, r, g);                     // z / sqrt(t)
            h = fmaf(r * r, r, h);                 // t^-1.5
        }
#pragma unroll
        for (int off = 32; off; off >>= 1) {
            g += __shfl_xor(g, off, 64);
            h += __shfl_xor(h, off, 64);
        }
        y -= g * __builtin_amdgcn_rcpf(fmaxf(h, 1e-12f));
    }

    if (t == 0) out[b] = y;
}

extern "C" void kernel_launch(void* const* d_in, const int* in_sizes, int n_in,
                              void* d_out, int out_size, void* d_ws, size_t ws_size,
                              hipStream_t stream) {
    const float* x = (const float*)d_in[0];
    float* out = (float*)d_out;
    const int n_slices = in_sizes[0] >> 12;   // 4096 elements per slice
    robust_pool_kernel<<<n_slices, 64, 0, stream>>>(x, out);
}